// Round 5
// baseline (138.859 us; speedup 1.0000x reference)
//
#include <hip/hip_runtime.h>
#include <hip/hip_bf16.h>

// Problem: features_1 [1,20000,256] f32, features_2 [1,8192,256] f32, map21 [8192] int
#define PP      8192
#define DIM     256
#define DIMP    272              // 256 + 16 pad dims (norm embedding in 4 of them)
#define NKF     17               // K fragments of 16
#define GS      (32 * DIMP)      // 8704 bf16 elems per 32-row group
#define NCHUNK  16               // column chunks (grid.y); chunk = 512 cols
#define TCOLS   16               // 32-col tiles per chunk
#define ROWBLK  128              // rows per main block (4 waves x 32 rows each)
#define NROWBLK (PP / ROWBLK)    // 64
#define TILEB   (32 * DIMP * 2)  // 17408 B per 32-col B tile
#define NBUF    2                // LDS ring buffers (depth-1 prefetch, counted)

typedef __bf16 bf16_t;
using bf16x8 = __attribute__((ext_vector_type(8))) __bf16;
using bf16x4 = __attribute__((ext_vector_type(4))) __bf16;
using f32x4  = __attribute__((ext_vector_type(4))) float;
using f32x16 = __attribute__((ext_vector_type(16))) float;

typedef __attribute__((address_space(1))) void as1_void;
typedef __attribute__((address_space(3))) void as3_void;

#define C2    20.609929155556618          // 1/(T*ln2): -dist -> log2-domain logit
#define MEXP  (-340.0f)                   // fixed log2 shift (safe: see analysis)
#define COEF  ((float)(-(C2 * 1.4142135623730951) * 8388608.0))  // -C2*sqrt(2)*2^23
#define KBIAS ((float)((127.0 + 340.0) * 8388608.0))             // (127 - MEXP)*2^23
#define LN2   0.6931471805599453f

// ---------------------------------------------------------------------------
// Kernel 1: gather + bf16 convert into frag-major layout + norm-embedding pad
// dims + exact fp32 diagonal logit. Also zero-inits part_l / counters / out.
// One wave per row p; lane covers k = lane*4 .. +3.   (UNCHANGED)
// ---------------------------------------------------------------------------
__global__ __launch_bounds__(256) void nce_prep(
    const float* __restrict__ f1, const float* __restrict__ f2,
    const int* __restrict__ map,
    bf16_t* __restrict__ qb2, bf16_t* __restrict__ kb2,
    float* __restrict__ diag2, float* __restrict__ part_l,
    unsigned* __restrict__ cnt, float* __restrict__ out)
{
    const int tid  = threadIdx.x;
    const int wave = tid >> 6, lane = tid & 63;
    const int p    = blockIdx.x * 4 + wave;
    const int gtid = blockIdx.x * 256 + tid;

    if (gtid < PP) part_l[gtid] = 0.0f;
    if (gtid < NROWBLK) cnt[gtid] = 0u;
    if (gtid == 0) out[0] = 0.0f;

    const int idx = map[p];
    const f32x4 qv = *(const f32x4*)(f1 + (size_t)idx * DIM + lane * 4);
    const f32x4 kv = *(const f32x4*)(f2 + (size_t)p * DIM + lane * 4);

    float qs = qv[0]*qv[0] + qv[1]*qv[1] + qv[2]*qv[2] + qv[3]*qv[3];
    float ks = kv[0]*kv[0] + kv[1]*kv[1] + kv[2]*kv[2] + kv[3]*kv[3];
    const f32x4 dv = qv - kv;
    float ds = dv[0]*dv[0] + dv[1]*dv[1] + dv[2]*dv[2] + dv[3]*dv[3];

    bf16x4 qo, ko;
    #pragma unroll
    for (int i = 0; i < 4; ++i) { qo[i] = (bf16_t)qv[i]; ko[i] = (bf16_t)kv[i]; }

    const int G = p >> 5, l31 = p & 31;
    const int kk = lane >> 2, h = (lane >> 1) & 1, j0 = (lane & 1) * 4;
    const size_t base = (size_t)G * GS;
    const size_t off  = base + (size_t)(kk * 64 + h * 32 + l31) * 8 + j0;
    *(bf16x4*)(qb2 + off) = qo;
    *(bf16x4*)(kb2 + off) = ko;

    #pragma unroll
    for (int s = 32; s > 0; s >>= 1) {
        qs += __shfl_xor(qs, s);
        ks += __shfl_xor(ks, s);
        ds += __shfl_xor(ds, s);
    }

    // Pad frag kk=16 (dims 256..271). q' = [qhi,qlo,1,1,0..], k' = [1,1,khi,klo,0..]
    // so extra-dim dot = -(qs+ks)/2 with bf16 hi/lo split (norm error < 0.01).
    if (lane < 4) {
        const int hh = lane & 1;           // h of the pad block this lane writes
        bf16x8 v;
        #pragma unroll
        for (int i = 0; i < 8; ++i) v[i] = (bf16_t)0.0f;
        if (lane == 0) {                   // q', dims 256..263
            const float qh = -0.5f * qs;
            const bf16_t q1 = (bf16_t)qh;
            v[0] = q1; v[1] = (bf16_t)(qh - (float)q1);
            v[2] = (bf16_t)1.0f; v[3] = (bf16_t)1.0f;
        } else if (lane == 2) {            // k', dims 256..263
            const float kh = -0.5f * ks;
            const bf16_t k1 = (bf16_t)kh;
            v[0] = (bf16_t)1.0f; v[1] = (bf16_t)1.0f;
            v[2] = k1; v[3] = (bf16_t)(kh - (float)k1);
        }
        bf16_t* dstp = (lane < 2) ? qb2 : kb2;
        *(bf16x8*)(dstp + base + (size_t)(1024 + hh * 32 + l31) * 8) = v;
    }
    if (lane == 0)
        diag2[p] = (float)(-C2) * __builtin_amdgcn_sqrtf(ds);  // exact diag, log2
}

// ---------------------------------------------------------------------------
// Stage one 32-col B tile (17408 B, frag-major) into LDS via global_load_lds
// width-16. LDS dst = wave-uniform base (+ implicit lane*16).
// Waves 0-3 load 4x1KB each; wave 0 loads the 17th-fragment KB extra (5 loads).
// ---------------------------------------------------------------------------
__device__ __forceinline__ void stage(const bf16_t* __restrict__ kb2,
                                      int Gc, int wave, int lane, char* dst)
{
    __builtin_assume(wave >= 0 && wave < 4);
    __builtin_assume(lane >= 0 && lane < 64);
    const bf16_t* src = kb2 + (size_t)Gc * GS + wave * 512 + lane * 8;
    char* d = dst + wave * 1024;
    #pragma unroll
    for (int j = 0; j < 4; ++j)
        __builtin_amdgcn_global_load_lds((const as1_void*)(src + j * 2048),
                                         (as3_void*)(d + j * 4096), 16, 0, 0);
    if (wave == 0)   // last 1 KB (17th fragment block)
        __builtin_amdgcn_global_load_lds((const as1_void*)(src + 4 * 2048),
                                         (as3_void*)(d + 4 * 4096), 16, 0, 0);
}

// ---------------------------------------------------------------------------
// One pipeline phase (macro: l[]/a[] stay constant-indexed locals — function
// version spilled in round 2).  Order as round 4 (ledger unchanged):
//   1. lgkmcnt(0)+s_barrier   2. stage(T+1)   3. vmcnt(4)
//   4. ds_read + MFMA under setprio(1)        5. sqrt/exp2 epilogue.
// ROUND-5 CHANGE: the 17-deep SERIAL acc chain is split into 4 INDEPENDENT
// chains (kk mod 4; depths 5/4/4/4).  Theory: dependent 32x32x16 MFMA
// latency ~64-80cy caps MfmaUtil at waves*chains*8/L — 3 structures all
// measured 24-27% as predicted by a single serial chain at ~2 waves/SIMD.
// 4 chains * 2 waves/SIMD should approach issue-bound.  Chains are combined
// (3 adds/elem) before the epilogue.
// ---------------------------------------------------------------------------
#define PHASE(NW, DOPRE, T)                                                    \
  do {                                                                         \
    asm volatile("s_waitcnt lgkmcnt(0)\n\ts_barrier" ::: "memory");            \
    if (DOPRE) stage(kb2, c0g + (T) + 1, wave, lane, smem[((T) + 1) & 1]);     \
    asm volatile("s_waitcnt vmcnt(%c0)" :: "i"(NW) : "memory");                \
    const bf16_t* bp = (const bf16_t*)smem[(T) & 1] + lane * 8;                \
    f32x16 acA = {0,0,0,0,0,0,0,0,0,0,0,0,0,0,0,0};                           \
    f32x16 acB = {0,0,0,0,0,0,0,0,0,0,0,0,0,0,0,0};                           \
    f32x16 acC = {0,0,0,0,0,0,0,0,0,0,0,0,0,0,0,0};                           \
    f32x16 acD = {0,0,0,0,0,0,0,0,0,0,0,0,0,0,0,0};                           \
    __builtin_amdgcn_s_setprio(1);                                             \
    _Pragma("unroll")                                                          \
    for (int kk = 0; kk < NKF; ++kk) {                                         \
        const bf16x8 b = *(const bf16x8*)(bp + kk * 512);                      \
        if ((kk & 3) == 0)                                                     \
            acA = __builtin_amdgcn_mfma_f32_32x32x16_bf16(a[kk], b, acA,0,0,0);\
        else if ((kk & 3) == 1)                                                \
            acB = __builtin_amdgcn_mfma_f32_32x32x16_bf16(a[kk], b, acB,0,0,0);\
        else if ((kk & 3) == 2)                                                \
            acC = __builtin_amdgcn_mfma_f32_32x32x16_bf16(a[kk], b, acC,0,0,0);\
        else                                                                   \
            acD = __builtin_amdgcn_mfma_f32_32x32x16_bf16(a[kk], b, acD,0,0,0);\
    }                                                                          \
    __builtin_amdgcn_s_setprio(0);                                             \
    /* combine chains; acc = -dist^2/2.  2^(lg-MEXP) bitcast; neg -> clamp */  \
    _Pragma("unroll")                                                          \
    for (int i = 0; i < 16; ++i) {                                             \
        const float sacc = (acA[i] + acB[i]) + (acC[i] + acD[i]);              \
        const float tt = __builtin_amdgcn_sqrtf(-sacc);                        \
        const float uu = fmaxf(fmaf(tt, COEF, KBIAS), 0.0f);                   \
        l[i] += __uint_as_float((unsigned)uu);                                 \
    }                                                                          \
  } while (0)

// ---------------------------------------------------------------------------
// Kernel 2: fused (QK' GEMM -> -dist^2/2) + fixed-shift exp2 accumulation +
// cross-block merge via atomicAdd + last-block final loss reduction.
// Wave = ONE 32-row group x 32 cols; block = 4 waves = 128 rows; grid 64x16,
// XCD-swizzled.  NBUF=2 counted-vmcnt ring (ledger in PHASE comment).
// launch_bounds(256,2): ~208 total regs/wave (60 VGPR + ~132 AGPR) -> 2
// waves/SIMD without forcing spill (the (256,4) cap would).
// ---------------------------------------------------------------------------
__global__ __launch_bounds__(256, 2) void nce_main(
    const bf16_t* __restrict__ qb2, const bf16_t* __restrict__ kb2,
    const float* __restrict__ diag2, float* __restrict__ part_l,
    unsigned* __restrict__ cnt, float* __restrict__ out)
{
    const int tid  = threadIdx.x, wave = tid >> 6, lane = tid & 63;
    const int l31  = lane & 31, h = lane >> 5;

    // bijective XCD swizzle: lin%8 = XCD (HW round-robin); XCD (xr,xc) owns
    // rb in [xr*16,xr*16+16) x cy in [xc*8,xc*8+8)  (xr=xcd&3, xc=xcd>>2)
    const int lin = blockIdx.x + (blockIdx.y << 6);   // gridDim.x = 64
    const int xcd = lin & 7, idx = lin >> 3;          // idx 0..127
    const int rb  = (xcd & 3) * 16 + (idx & 15);      // row-block 0..63
    const int cy  = (xcd >> 2) * 8 + (idx >> 4);      // chunk 0..15
    const int G0  = rb * 4 + wave;                    // this wave's 32-row group
    const int c0g = cy * TCOLS;                       // first col-group of chunk

    __shared__ __align__(16) char smem[NBUF][TILEB];
    __shared__ int s_last;
    __shared__ float red[4];

    // prologue: stage tile 0 (loads in flight behind the A-loads)
    stage(kb2, c0g, wave, lane, smem[0]);

    // A fragments for ONE row group: 17 x 4 = 68 regs, 1KB/instr coalesced
    bf16x8 a[NKF];
    {
        const bf16_t* ap = qb2 + (size_t)G0 * GS + lane * 8;
        #pragma unroll
        for (int kk = 0; kk < NKF; ++kk)
            a[kk] = *(const bf16x8*)(ap + kk * 512);
    }

    float l[16];
    #pragma unroll
    for (int i = 0; i < 16; ++i) l[i] = 0.0f;

    // steady state (rolled — full unroll spilled in round 2)
    #pragma unroll 1
    for (int t = 0; t < TCOLS - 1; ++t)
        PHASE(4, true, t);
    PHASE(0, false, TCOLS - 1);   // drain tail

    // sum l across the 32 column-lanes (plain adds — fixed shift, no max merge)
    #pragma unroll
    for (int s = 1; s < 32; s <<= 1) {
        #pragma unroll
        for (int i = 0; i < 16; ++i)
            l[i] += __shfl_xor(l[i], s);
    }

    if (l31 == 0) {
        #pragma unroll
        for (int i = 0; i < 16; ++i) {
            const int r = (i & 3) + 8 * (i >> 2) + 4 * h;
            atomicAdd(&part_l[G0 * 32 + r], l[i]);
        }
    }

    __syncthreads();
    if (tid == 0) {
        __threadfence();
        s_last = (atomicAdd(&cnt[rb], 1u) == NCHUNK - 1) ? 1 : 0;
    }
    __syncthreads();
    if (s_last) {
        // all 16 chunk-blocks of this row-block done: finalize 128 rows
        float v = 0.0f;
        if (tid < ROWBLK) {
            const int row = rb * ROWBLK + tid;
            const float lf = atomicAdd(&part_l[row], 0.0f);   // coherent read
            v = MEXP + __builtin_amdgcn_logf(lf) - diag2[row];  // log2 domain
        }
        #pragma unroll
        for (int s = 1; s < 64; s <<= 1) v += __shfl_xor(v, s);
        if (lane == 0) red[wave] = v;
        __syncthreads();
        if (tid == 0)
            atomicAdd(out, (red[0] + red[1] + red[2] + red[3]) * (LN2 / (float)PP));
    }
}

// ---------------------------------------------------------------------------
extern "C" void kernel_launch(void* const* d_in, const int* in_sizes, int n_in,
                              void* d_out, int out_size, void* d_ws, size_t ws_size,
                              hipStream_t stream)
{
    const float* f1  = (const float*)d_in[0];   // [20000,256] f32
    const float* f2  = (const float*)d_in[1];   // [8192,256] f32
    const int*   map = (const int*)d_in[2];     // [8192] int
    float* out = (float*)d_out;

    // workspace layout (~8.98 MB)
    char* ws = (char*)d_ws;
    bf16_t*   qb2    = (bf16_t*)ws;                           // 256*8704*2 B
    bf16_t*   kb2    = qb2 + (size_t)256 * GS;                // 256*8704*2 B
    float*    diag2  = (float*)(ws + 2ull * 256 * GS * sizeof(bf16_t));
    float*    part_l = diag2 + PP;
    unsigned* cnt    = (unsigned*)(part_l + PP);

    nce_prep<<<PP / 4, 256, 0, stream>>>(f1, f2, map, qb2, kb2, diag2,
                                         part_l, cnt, out);
    nce_main<<<dim3(NROWBLK, NCHUNK), 256, 0, stream>>>(qb2, kb2, diag2,
                                                        part_l, cnt, out);
}

// Round 6
// 120.279 us; speedup vs baseline: 1.1545x; 1.1545x over previous
//
#include <hip/hip_runtime.h>
#include <hip/hip_bf16.h>

// Problem: features_1 [1,20000,256] f32, features_2 [1,8192,256] f32, map21 [8192] int
#define PP      8192
#define DIM     256
#define DIMP    272              // 256 + 16 pad dims (norm embedding in 4 of them)
#define NKF     17               // K fragments of 16
#define GS      (32 * DIMP)      // 8704 bf16 elems per 32-row group
#define NCHUNK  16               // column chunks (grid.y); chunk = 512 cols
#define TCOLS   16               // 32-col tiles per chunk
#define ROWBLK  256              // rows per main block (4 waves x 2 row-groups)
#define NROWBLK (PP / ROWBLK)    // 32
#define TILEB   (32 * DIMP * 2)  // 17408 B per 32-col B tile
#define NBUF    2                // LDS ring buffers (depth-1 prefetch, counted)

typedef __bf16 bf16_t;
using bf16x8 = __attribute__((ext_vector_type(8))) __bf16;
using bf16x4 = __attribute__((ext_vector_type(4))) __bf16;
using f32x4  = __attribute__((ext_vector_type(4))) float;
using f32x16 = __attribute__((ext_vector_type(16))) float;

typedef __attribute__((address_space(1))) void as1_void;
typedef __attribute__((address_space(3))) void as3_void;

#define C2    20.609929155556618          // 1/(T*ln2): -dist -> log2-domain logit
#define MEXP  (-340.0f)                   // fixed log2 shift (safe: see analysis)
#define COEF  ((float)(-(C2 * 1.4142135623730951) * 8388608.0))  // -C2*sqrt(2)*2^23
#define KBIAS ((float)((127.0 + 340.0) * 8388608.0))             // (127 - MEXP)*2^23
#define LN2   0.6931471805599453f

// ---------------------------------------------------------------------------
// Kernel 1: gather + bf16 convert into frag-major layout + norm-embedding pad
// dims + exact fp32 diagonal logit. Also zero-inits part_l / counters / out.
// One wave per row p; lane covers k = lane*4 .. +3.   (UNCHANGED)
// ---------------------------------------------------------------------------
__global__ __launch_bounds__(256) void nce_prep(
    const float* __restrict__ f1, const float* __restrict__ f2,
    const int* __restrict__ map,
    bf16_t* __restrict__ qb2, bf16_t* __restrict__ kb2,
    float* __restrict__ diag2, float* __restrict__ part_l,
    unsigned* __restrict__ cnt, float* __restrict__ out)
{
    const int tid  = threadIdx.x;
    const int wave = tid >> 6, lane = tid & 63;
    const int p    = blockIdx.x * 4 + wave;
    const int gtid = blockIdx.x * 256 + tid;

    if (gtid < PP) part_l[gtid] = 0.0f;
    if (gtid < NROWBLK) cnt[gtid] = 0u;
    if (gtid == 0) out[0] = 0.0f;

    const int idx = map[p];
    const f32x4 qv = *(const f32x4*)(f1 + (size_t)idx * DIM + lane * 4);
    const f32x4 kv = *(const f32x4*)(f2 + (size_t)p * DIM + lane * 4);

    float qs = qv[0]*qv[0] + qv[1]*qv[1] + qv[2]*qv[2] + qv[3]*qv[3];
    float ks = kv[0]*kv[0] + kv[1]*kv[1] + kv[2]*kv[2] + kv[3]*kv[3];
    const f32x4 dv = qv - kv;
    float ds = dv[0]*dv[0] + dv[1]*dv[1] + dv[2]*dv[2] + dv[3]*dv[3];

    bf16x4 qo, ko;
    #pragma unroll
    for (int i = 0; i < 4; ++i) { qo[i] = (bf16_t)qv[i]; ko[i] = (bf16_t)kv[i]; }

    const int G = p >> 5, l31 = p & 31;
    const int kk = lane >> 2, h = (lane >> 1) & 1, j0 = (lane & 1) * 4;
    const size_t base = (size_t)G * GS;
    const size_t off  = base + (size_t)(kk * 64 + h * 32 + l31) * 8 + j0;
    *(bf16x4*)(qb2 + off) = qo;
    *(bf16x4*)(kb2 + off) = ko;

    #pragma unroll
    for (int s = 32; s > 0; s >>= 1) {
        qs += __shfl_xor(qs, s);
        ks += __shfl_xor(ks, s);
        ds += __shfl_xor(ds, s);
    }

    // Pad frag kk=16 (dims 256..271). q' = [qhi,qlo,1,1,0..], k' = [1,1,khi,klo,0..]
    // so extra-dim dot = -(qs+ks)/2 with bf16 hi/lo split (norm error < 0.01).
    if (lane < 4) {
        const int hh = lane & 1;           // h of the pad block this lane writes
        bf16x8 v;
        #pragma unroll
        for (int i = 0; i < 8; ++i) v[i] = (bf16_t)0.0f;
        if (lane == 0) {                   // q', dims 256..263
            const float qh = -0.5f * qs;
            const bf16_t q1 = (bf16_t)qh;
            v[0] = q1; v[1] = (bf16_t)(qh - (float)q1);
            v[2] = (bf16_t)1.0f; v[3] = (bf16_t)1.0f;
        } else if (lane == 2) {            // k', dims 256..263
            const float kh = -0.5f * ks;
            const bf16_t k1 = (bf16_t)kh;
            v[0] = (bf16_t)1.0f; v[1] = (bf16_t)1.0f;
            v[2] = k1; v[3] = (bf16_t)(kh - (float)k1);
        }
        bf16_t* dstp = (lane < 2) ? qb2 : kb2;
        *(bf16x8*)(dstp + base + (size_t)(1024 + hh * 32 + l31) * 8) = v;
    }
    if (lane == 0)
        diag2[p] = (float)(-C2) * __builtin_amdgcn_sqrtf(ds);  // exact diag, log2
}

// ---------------------------------------------------------------------------
// Stage one 32-col B tile (17408 B, frag-major) into LDS via global_load_lds
// width-16. LDS dst = wave-uniform base (+ implicit lane*16).
// Waves 0-3 load 4x1KB each; wave 0 loads the 17th-fragment KB extra (5 loads).
// ---------------------------------------------------------------------------
__device__ __forceinline__ void stage(const bf16_t* __restrict__ kb2,
                                      int Gc, int wave, int lane, char* dst)
{
    __builtin_assume(wave >= 0 && wave < 4);
    __builtin_assume(lane >= 0 && lane < 64);
    const bf16_t* src = kb2 + (size_t)Gc * GS + wave * 512 + lane * 8;
    char* d = dst + wave * 1024;
    #pragma unroll
    for (int j = 0; j < 4; ++j)
        __builtin_amdgcn_global_load_lds((const as1_void*)(src + j * 2048),
                                         (as3_void*)(d + j * 4096), 16, 0, 0);
    if (wave == 0)   // last 1 KB (17th fragment block)
        __builtin_amdgcn_global_load_lds((const as1_void*)(src + 4 * 2048),
                                         (as3_void*)(d + 4 * 4096), 16, 0, 0);
}

// ---------------------------------------------------------------------------
// One pipeline phase (macro: l/a stay constant-indexed locals — function
// version spilled in round 2).  RG=2: each ds_read_b128 B-frag feeds TWO
// MFMAs (a0,a1 row-groups) — halves the per-output LDS read traffic.
// LDS-pipe model (fits R4/R5): a wave reads the whole 17 KB B-tile per
// phase regardless of RG; 4 SIMDs share one LDS pipe -> MfmaUtil cap =
// RG/4.  RG=1 capped at ~25% (R4 measured 24 at its roofline); RG=2
// raises the cap to ~50%, provided 2 waves/SIMD exist to cover latency.
// Order (ledger identical to R4):
//   1. lgkmcnt(0)+s_barrier   2. stage(T+1)   3. vmcnt(4)
//   4. ds_read + dual MFMA chains under setprio(1)   5. sqrt/exp2 epilogue
// Phase 0: vmcnt(4) also retires the 34 A-fragment loads (they precede
// stage(1) in program order; in-order retirement).  Tail: vmcnt(0).
// ---------------------------------------------------------------------------
#define PHASE(NW, DOPRE, T)                                                    \
  do {                                                                         \
    asm volatile("s_waitcnt lgkmcnt(0)\n\ts_barrier" ::: "memory");            \
    if (DOPRE) stage(kb2, c0g + (T) + 1, wave, lane, smem[((T) + 1) & 1]);     \
    asm volatile("s_waitcnt vmcnt(%c0)" :: "i"(NW) : "memory");                \
    const bf16_t* bp = (const bf16_t*)smem[(T) & 1] + lane * 8;                \
    f32x16 acc0 = {0,0,0,0,0,0,0,0,0,0,0,0,0,0,0,0};                          \
    f32x16 acc1 = {0,0,0,0,0,0,0,0,0,0,0,0,0,0,0,0};                          \
    __builtin_amdgcn_s_setprio(1);                                             \
    _Pragma("unroll")                                                          \
    for (int kk = 0; kk < NKF; ++kk) {                                         \
        const bf16x8 b = *(const bf16x8*)(bp + kk * 512);                      \
        acc0 = __builtin_amdgcn_mfma_f32_32x32x16_bf16(a0[kk], b, acc0,0,0,0); \
        acc1 = __builtin_amdgcn_mfma_f32_32x32x16_bf16(a1[kk], b, acc1,0,0,0); \
    }                                                                          \
    __builtin_amdgcn_s_setprio(0);                                             \
    /* acc = -dist^2/2.  2^(lg-MEXP) bitcast trick; negative -> clamp 0 */     \
    _Pragma("unroll")                                                          \
    for (int i = 0; i < 16; ++i) {                                             \
        const float t0 = __builtin_amdgcn_sqrtf(-acc0[i]);                     \
        const float u0 = fmaxf(fmaf(t0, COEF, KBIAS), 0.0f);                   \
        l0[i] += __uint_as_float((unsigned)u0);                                \
        const float t1 = __builtin_amdgcn_sqrtf(-acc1[i]);                     \
        const float u1 = fmaxf(fmaf(t1, COEF, KBIAS), 0.0f);                   \
        l1[i] += __uint_as_float((unsigned)u1);                                \
    }                                                                          \
  } while (0)

// ---------------------------------------------------------------------------
// Kernel 2: fused (QK' GEMM -> -dist^2/2) + fixed-shift exp2 accumulation +
// cross-block merge via atomicAdd + last-block final loss reduction.
// Wave = 64 rows (2 groups, RG=2) x 32 cols; block = 4 waves = 256 rows.
// Grid 32x16 = 512 blocks = 2 blocks/CU -> 2 desynced waves/SIMD (separate
// barriers) to overlap one block's VALU epilogue with the other's MFMA.
// NBUF=2 counted-vmcnt ring, XCD swizzle (3.3 MB/XCD working set < 4MB L2).
// Register ledger: a0/a1 136 + acc 32 + l 32 + ~30 temps ~ 230 <= 256/wave.
// ---------------------------------------------------------------------------
__global__ __launch_bounds__(256, 2) void nce_main(
    const bf16_t* __restrict__ qb2, const bf16_t* __restrict__ kb2,
    const float* __restrict__ diag2, float* __restrict__ part_l,
    unsigned* __restrict__ cnt, float* __restrict__ out)
{
    const int tid  = threadIdx.x, wave = tid >> 6, lane = tid & 63;
    const int l31  = lane & 31, h = lane >> 5;

    // bijective XCD swizzle: lin%8 = XCD (HW round-robin); XCD (xr,xc) owns
    // rb in [xr*8,xr*8+8) x cy in [xc*8,xc*8+8)  (xr=xcd&3, xc=xcd>>2)
    const int lin = blockIdx.x + (blockIdx.y << 5);   // gridDim.x = 32
    const int xcd = lin & 7, idx = lin >> 3;          // idx 0..63
    const int rb  = (xcd & 3) * 8 + (idx & 7);        // row-block 0..31
    const int cy  = (xcd >> 2) * 8 + (idx >> 3);      // chunk 0..15
    const int G0  = rb * 8 + wave * 2;                // wave's first 32-row group
    const int c0g = cy * TCOLS;                       // first col-group of chunk

    __shared__ __align__(16) char smem[NBUF][TILEB];
    __shared__ int s_last;
    __shared__ float red[4];

    // prologue: stage tile 0 (loads in flight ahead of the A-loads)
    stage(kb2, c0g, wave, lane, smem[0]);

    // A fragments for 2 row groups: 2 x 17 x 4 = 136 regs, 1KB/instr coalesced
    bf16x8 a0[NKF], a1[NKF];
    {
        const bf16_t* ap0 = qb2 + (size_t)G0 * GS + lane * 8;
        const bf16_t* ap1 = ap0 + GS;
        #pragma unroll
        for (int kk = 0; kk < NKF; ++kk) {
            a0[kk] = *(const bf16x8*)(ap0 + kk * 512);
            a1[kk] = *(const bf16x8*)(ap1 + kk * 512);
        }
    }

    float l0[16], l1[16];
    #pragma unroll
    for (int i = 0; i < 16; ++i) { l0[i] = 0.0f; l1[i] = 0.0f; }

    // steady state (rolled — full unroll spilled in round 2)
    #pragma unroll 1
    for (int t = 0; t < TCOLS - 1; ++t)
        PHASE(4, true, t);
    PHASE(0, false, TCOLS - 1);   // drain tail

    // sum l across the 32 column-lanes (plain adds — fixed shift, no max merge)
    #pragma unroll
    for (int s = 1; s < 32; s <<= 1) {
        #pragma unroll
        for (int i = 0; i < 16; ++i) {
            l0[i] += __shfl_xor(l0[i], s);
            l1[i] += __shfl_xor(l1[i], s);
        }
    }

    if (l31 == 0) {
        #pragma unroll
        for (int i = 0; i < 16; ++i) {
            const int r = (i & 3) + 8 * (i >> 2) + 4 * h;
            atomicAdd(&part_l[G0 * 32 + r], l0[i]);
            atomicAdd(&part_l[(G0 + 1) * 32 + r], l1[i]);
        }
    }

    __syncthreads();
    if (tid == 0) {
        __threadfence();
        s_last = (atomicAdd(&cnt[rb], 1u) == NCHUNK - 1) ? 1 : 0;
    }
    __syncthreads();
    if (s_last) {
        // all 16 chunk-blocks of this row-block done: finalize 256 rows
        const int row = rb * ROWBLK + tid;
        const float lf = atomicAdd(&part_l[row], 0.0f);   // coherent read
        float v = MEXP + __builtin_amdgcn_logf(lf) - diag2[row];  // log2 domain
        #pragma unroll
        for (int s = 1; s < 64; s <<= 1) v += __shfl_xor(v, s);
        if (lane == 0) red[wave] = v;
        __syncthreads();
        if (tid == 0)
            atomicAdd(out, (red[0] + red[1] + red[2] + red[3]) * (LN2 / (float)PP));
    }
}

// ---------------------------------------------------------------------------
extern "C" void kernel_launch(void* const* d_in, const int* in_sizes, int n_in,
                              void* d_out, int out_size, void* d_ws, size_t ws_size,
                              hipStream_t stream)
{
    const float* f1  = (const float*)d_in[0];   // [20000,256] f32
    const float* f2  = (const float*)d_in[1];   // [8192,256] f32
    const int*   map = (const int*)d_in[2];     // [8192] int
    float* out = (float*)d_out;

    // workspace layout (~8.98 MB)
    char* ws = (char*)d_ws;
    bf16_t*   qb2    = (bf16_t*)ws;                           // 256*8704*2 B
    bf16_t*   kb2    = qb2 + (size_t)256 * GS;                // 256*8704*2 B
    float*    diag2  = (float*)(ws + 2ull * 256 * GS * sizeof(bf16_t));
    float*    part_l = diag2 + PP;
    unsigned* cnt    = (unsigned*)(part_l + PP);

    nce_prep<<<PP / 4, 256, 0, stream>>>(f1, f2, map, qb2, kb2, diag2,
                                         part_l, cnt, out);
    nce_main<<<dim3(NROWBLK, NCHUNK), 256, 0, stream>>>(qb2, kb2, diag2,
                                                        part_l, cnt, out);
}